// Round 1
// baseline (344.900 us; speedup 1.0000x reference)
//
#include <hip/hip_runtime.h>
#include <math.h>

#define NEG_HUGE -1e30f
constexpr int B_ = 64, H_ = 128, C_ = 1024, Q_ = 128;

// ---------------------------------------------------------------------------
// K0: s1b[b,q] = bias + sum_h q[b,h,q] * query_weights[h]
// ---------------------------------------------------------------------------
__global__ __launch_bounds__(128) void k0_s1b(
    const float* __restrict__ qin, const float* __restrict__ qw,
    const float* __restrict__ bias, float* __restrict__ s1b) {
  const int b = blockIdx.x, qq = threadIdx.x;
  const float* qb = qin + (size_t)b * H_ * Q_;
  float acc = 0.f;
#pragma unroll 8
  for (int h = 0; h < H_; ++h) acc += qb[(size_t)h * Q_ + qq] * qw[h];
  s1b[b * Q_ + qq] = acc + bias[0];
}

// ---------------------------------------------------------------------------
// K1: S[b,c,q] = s0[c] + s1b[q] + sum_h c[b,h,c]*cqw[h]*q[b,h,q]
// grid (C/128, B), block 256; 128c x 128q tile, 8x8 per thread, K-chunk 32.
// ---------------------------------------------------------------------------
__global__ __launch_bounds__(256) void k1_S(
    const float* __restrict__ cin, const float* __restrict__ qin,
    const float* __restrict__ ctxw, const float* __restrict__ cqw,
    const float* __restrict__ s1b, float* __restrict__ S) {
  __shared__ float craw[32][132];   // [h-chunk][c] raw c values
  __shared__ float qpre[32][132];   // [h-chunk][q] q*cqw
  __shared__ float s1L[128];
  __shared__ float s0arr[128];
  __shared__ float redbuf[256];

  const int t = threadIdx.x;
  const int b = blockIdx.y, c0 = blockIdx.x * 128;
  const int tc = t & 15, tq = t >> 4;
  const float* cb = cin + ((size_t)b * H_) * C_ + c0;
  const float* qb = qin + ((size_t)b * H_) * Q_;

  if (t < 128) s1L[t] = s1b[b * Q_ + t];

  float acc[8][8];
#pragma unroll
  for (int i = 0; i < 8; ++i)
#pragma unroll
    for (int j = 0; j < 8; ++j) acc[i][j] = 0.f;

  float s0part = 0.f;

  for (int hc = 0; hc < 4; ++hc) {
    __syncthreads();
#pragma unroll
    for (int r = 0; r < 16; ++r) {
      int idx = t + 256 * r;
      int cc = idx & 127, hh = idx >> 7;
      float v = cb[(size_t)(hc * 32 + hh) * C_ + cc];
      craw[hh][cc] = v;
      s0part += v * ctxw[hc * 32 + hh];  // partial s0 for cc = t&127
    }
#pragma unroll
    for (int r = 0; r < 16; ++r) {
      int idx = t + 256 * r;
      int qq = idx & 127, hh = idx >> 7;
      qpre[hh][qq] = qb[(size_t)(hc * 32 + hh) * Q_ + qq] * cqw[hc * 32 + hh];
    }
    __syncthreads();
#pragma unroll
    for (int hh = 0; hh < 32; ++hh) {
      float cv[8], qv[8];
      *(float4*)&cv[0] = *(const float4*)&craw[hh][tc * 4];
      *(float4*)&cv[4] = *(const float4*)&craw[hh][64 + tc * 4];
      *(float4*)&qv[0] = *(const float4*)&qpre[hh][tq * 8];
      *(float4*)&qv[4] = *(const float4*)&qpre[hh][tq * 8 + 4];
#pragma unroll
      for (int i = 0; i < 8; ++i)
#pragma unroll
        for (int j = 0; j < 8; ++j) acc[i][j] += cv[i] * qv[j];
    }
  }
  // s0 pair-reduce: threads t and t+128 staged the same cc = t&127
  redbuf[t] = s0part;
  __syncthreads();
  if (t < 128) s0arr[t] = redbuf[t] + redbuf[t + 128];
  __syncthreads();

  float* Sb = S + ((size_t)b * C_ + c0) * Q_;
#pragma unroll
  for (int i = 0; i < 8; ++i) {
    int ci = (i < 4) ? (tc * 4 + i) : (64 + tc * 4 + (i - 4));
    float s0v = s0arr[ci];
    float o[8];
#pragma unroll
    for (int j = 0; j < 8; ++j) o[j] = acc[i][j] + s0v + s1L[tq * 8 + j];
    float* row = Sb + (size_t)ci * Q_ + tq * 8;
    *(float4*)&row[0] = *(float4*)&o[0];
    *(float4*)&row[4] = *(float4*)&o[4];
  }
}

// ---------------------------------------------------------------------------
// K2: row softmax stats (over q, with q_mask) + column partial stats
// (over 64-c chunk, with c_mask). grid (C/64, B), block 256.
// ---------------------------------------------------------------------------
__global__ __launch_bounds__(256) void k2_stats(
    const float* __restrict__ S, const float* __restrict__ cmask,
    const float* __restrict__ qmask,
    float* __restrict__ rowmax, float* __restrict__ rowsum,
    float* __restrict__ partmax, float* __restrict__ partsum) {
  __shared__ float Sc[64][129];
  __shared__ float qmA[128];
  __shared__ float cmA[64];
  const int t = threadIdx.x;
  const int b = blockIdx.y, c0 = blockIdx.x * 64;
  const float* Sb = S + ((size_t)b * C_ + c0) * Q_;
  if (t < 128) qmA[t] = (qmask[b * Q_ + t] > 0.f) ? 0.f : NEG_HUGE;
  else if (t < 192) cmA[t - 128] = (cmask[b * C_ + c0 + (t - 128)] > 0.f) ? 0.f : NEG_HUGE;
#pragma unroll
  for (int r = 0; r < 32; ++r) {
    int idx = t + 256 * r;
    int qq = idx & 127, cc = idx >> 7;
    Sc[cc][qq] = Sb[(size_t)cc * Q_ + qq];
  }
  __syncthreads();
  if (t < 64) {  // row stats (softmax over q for a_att)
    float m = -INFINITY;
#pragma unroll 4
    for (int qq = 0; qq < 128; ++qq) m = fmaxf(m, Sc[t][qq] + qmA[qq]);
    float s = 0.f;
#pragma unroll 4
    for (int qq = 0; qq < 128; ++qq) s += __expf(Sc[t][qq] + qmA[qq] - m);
    rowmax[b * C_ + c0 + t] = m;
    rowsum[b * C_ + c0 + t] = s;
  } else if (t >= 128) {  // column partial stats (softmax over c for b_att)
    int qq = t - 128;
    float m = -INFINITY;
#pragma unroll 4
    for (int cc = 0; cc < 64; ++cc) m = fmaxf(m, Sc[cc][qq] + cmA[cc]);
    float s = 0.f;
#pragma unroll 4
    for (int cc = 0; cc < 64; ++cc) s += __expf(Sc[cc][qq] + cmA[cc] - m);
    partmax[((size_t)b * 16 + blockIdx.x) * Q_ + qq] = m;
    partsum[((size_t)b * 16 + blockIdx.x) * Q_ + qq] = s;
  }
}

// ---------------------------------------------------------------------------
// K2b: combine 16 column partials (streaming softmax merge). grid B, block 128.
// ---------------------------------------------------------------------------
__global__ __launch_bounds__(128) void k2b_combine(
    const float* __restrict__ partmax, const float* __restrict__ partsum,
    float* __restrict__ colmax, float* __restrict__ colsum) {
  const int b = blockIdx.x, qq = threadIdx.x;
  float M = -INFINITY;
#pragma unroll
  for (int k = 0; k < 16; ++k)
    M = fmaxf(M, partmax[((size_t)b * 16 + k) * Q_ + qq]);
  float s = 0.f;
#pragma unroll
  for (int k = 0; k < 16; ++k)
    s += partsum[((size_t)b * 16 + k) * Q_ + qq] *
         __expf(partmax[((size_t)b * 16 + k) * Q_ + qq] - M);
  colmax[b * Q_ + qq] = M;
  colsum[b * Q_ + qq] = s;
}

// ---------------------------------------------------------------------------
// K3: Tpart[kc][b,q,h] = sum_{c in chunk} exp(S+cmA-colmax) * cT[c,h]
// grid (4, B), block 256; 128q x 128h tile, 8x8 per thread, K-chunk 32.
// ---------------------------------------------------------------------------
__global__ __launch_bounds__(256) void k3_T(
    const float* __restrict__ S, const float* __restrict__ cin,
    const float* __restrict__ cmask, const float* __restrict__ colmax,
    float* __restrict__ Tpart) {
  __shared__ float eS[32][132];   // [c-chunk][q]
  __shared__ float cT[32][132];   // [c-chunk][h]
  __shared__ float cmaxL[128];
  const int t = threadIdx.x;
  const int kc = blockIdx.x, b = blockIdx.y;
  const int tq = t & 15, th = t >> 4;
  if (t < 128) cmaxL[t] = colmax[b * Q_ + t];
  const float* Sb = S + ((size_t)b * C_) * Q_;
  const float* cb = cin + ((size_t)b * H_) * C_;
  float acc[8][8];
#pragma unroll
  for (int i = 0; i < 8; ++i)
#pragma unroll
    for (int j = 0; j < 8; ++j) acc[i][j] = 0.f;

  for (int cc0 = kc * 256; cc0 < kc * 256 + 256; cc0 += 32) {
    __syncthreads();
#pragma unroll
    for (int r = 0; r < 16; ++r) {
      int idx = t + 256 * r;
      int qq = idx & 127, cc = idx >> 7;
      float cmv = (cmask[b * C_ + cc0 + cc] > 0.f) ? 0.f : NEG_HUGE;
      eS[cc][qq] = __expf(Sb[(size_t)(cc0 + cc) * Q_ + qq] + cmv - cmaxL[qq]);
    }
#pragma unroll
    for (int r = 0; r < 16; ++r) {
      int idx = t + 256 * r;
      int ci = idx & 31, hh = idx >> 5;
      cT[ci][hh] = cb[(size_t)hh * C_ + cc0 + ci];
    }
    __syncthreads();
#pragma unroll
    for (int cc = 0; cc < 32; ++cc) {
      float ev[8], hv[8];
      *(float4*)&ev[0] = *(const float4*)&eS[cc][tq * 4];
      *(float4*)&ev[4] = *(const float4*)&eS[cc][64 + tq * 4];
      *(float4*)&hv[0] = *(const float4*)&cT[cc][th * 8];
      *(float4*)&hv[4] = *(const float4*)&cT[cc][th * 8 + 4];
#pragma unroll
      for (int i = 0; i < 8; ++i)
#pragma unroll
        for (int j = 0; j < 8; ++j) acc[i][j] += ev[i] * hv[j];
    }
  }
  float* Tp = Tpart + ((size_t)(kc * B_ + b) * Q_) * H_;
#pragma unroll
  for (int i = 0; i < 8; ++i) {
    int qi = (i < 4) ? (tq * 4 + i) : (64 + tq * 4 + (i - 4));
    float* row = Tp + (size_t)qi * H_ + th * 8;
    *(float4*)&row[0] = *(float4*)&acc[i][0];
    *(float4*)&row[4] = *(float4*)&acc[i][4];
  }
}

// ---------------------------------------------------------------------------
// K3b: T = (sum of 4 partials) / colsum. grid 4096, block 256.
// ---------------------------------------------------------------------------
__global__ __launch_bounds__(256) void k3b_combine(
    const float* __restrict__ Tpart, const float* __restrict__ colsum,
    float* __restrict__ T) {
  const int gid = blockIdx.x * 256 + threadIdx.x;  // over B*Q*H
  const int bq = gid >> 7;                         // H == 128
  const float inv = 1.f / colsum[bq];
  float v = 0.f;
#pragma unroll
  for (int k = 0; k < 4; ++k) v += Tpart[(size_t)k * B_ * Q_ * H_ + gid];
  T[gid] = v * inv;
}

// ---------------------------------------------------------------------------
// K4: a = a_att @ qT, bvec = a_att @ T; emit [c, a, c*a, c*b].
// grid (C/128, 2, B), block 256; 128c x 64h tile, 8c x 4h x 2 accs per thread.
// ---------------------------------------------------------------------------
__global__ __launch_bounds__(256) void k4_out(
    const float* __restrict__ S, const float* __restrict__ qin,
    const float* __restrict__ cin, const float* __restrict__ T,
    const float* __restrict__ rowmax, const float* __restrict__ rowsum,
    const float* __restrict__ qmask, float* __restrict__ out) {
  __shared__ float Ae[32][132];  // [q-chunk][c] a_att
  __shared__ float Bq[32][68];   // [q-chunk][h] qT
  __shared__ float Bt[32][68];   // [q-chunk][h] T
  __shared__ float rmL[128], riL[128], qmL[128];
  const int t = threadIdx.x;
  const int c0 = blockIdx.x * 128, hb = blockIdx.y * 64, b = blockIdx.z;
  const int tc = t & 15, th = t >> 4;
  if (t < 128) {
    rmL[t] = rowmax[b * C_ + c0 + t];
    riL[t] = 1.f / rowsum[b * C_ + c0 + t];
    qmL[t] = (qmask[b * Q_ + t] > 0.f) ? 0.f : NEG_HUGE;
  }
  const float* Sb = S + ((size_t)b * C_ + c0) * Q_;
  const float* qb = qin + ((size_t)b * H_) * Q_;
  const float* Tb = T + ((size_t)b * Q_) * H_;
  float accA[8][4], accB[8][4];
#pragma unroll
  for (int i = 0; i < 8; ++i)
#pragma unroll
    for (int j = 0; j < 4; ++j) { accA[i][j] = 0.f; accB[i][j] = 0.f; }

  for (int qc = 0; qc < 4; ++qc) {
    __syncthreads();
#pragma unroll
    for (int r = 0; r < 16; ++r) {
      int idx = t + 256 * r;
      int qq = idx & 31, cc = idx >> 5;
      Ae[qq][cc] = __expf(Sb[(size_t)cc * Q_ + qc * 32 + qq] +
                          qmL[qc * 32 + qq] - rmL[cc]) * riL[cc];
    }
#pragma unroll
    for (int r = 0; r < 8; ++r) {
      int idx = t + 256 * r;
      int qq = idx & 31, hh = idx >> 5;
      Bq[qq][hh] = qb[(size_t)(hb + hh) * Q_ + qc * 32 + qq];
    }
#pragma unroll
    for (int r = 0; r < 8; ++r) {
      int idx = t + 256 * r;
      int hh = idx & 63, qq = idx >> 6;
      Bt[qq][hh] = Tb[(size_t)(qc * 32 + qq) * H_ + hb + hh];
    }
    __syncthreads();
#pragma unroll
    for (int qq = 0; qq < 32; ++qq) {
      float av[8];
      *(float4*)&av[0] = *(const float4*)&Ae[qq][tc * 4];
      *(float4*)&av[4] = *(const float4*)&Ae[qq][64 + tc * 4];
      float4 qv = *(const float4*)&Bq[qq][th * 4];
      float4 tv = *(const float4*)&Bt[qq][th * 4];
      const float* qvp = &qv.x;
      const float* tvp = &tv.x;
#pragma unroll
      for (int i = 0; i < 8; ++i)
#pragma unroll
        for (int j = 0; j < 4; ++j) {
          accA[i][j] += av[i] * qvp[j];
          accB[i][j] += av[i] * tvp[j];
        }
    }
  }

  float* ob = out + (size_t)b * (4 * H_) * C_;
#pragma unroll
  for (int j = 0; j < 4; ++j) {
    int h = hb + th * 4 + j;
    const float* crow = cin + ((size_t)b * H_ + h) * C_ + c0;
#pragma unroll
    for (int half = 0; half < 2; ++half) {
      int coff = half * 64 + tc * 4;
      float4 cv = *(const float4*)&crow[coff];
      const float* cvp = &cv.x;
      float oa[4], o2[4], o3[4];
#pragma unroll
      for (int i = 0; i < 4; ++i) {
        float av = accA[half * 4 + i][j];
        float bv = accB[half * 4 + i][j];
        oa[i] = av;
        o2[i] = cvp[i] * av;
        o3[i] = cvp[i] * bv;
      }
      size_t base = (size_t)h * C_ + c0 + coff;
      *(float4*)&ob[base] = cv;
      *(float4*)&ob[(size_t)128 * C_ + base] = *(float4*)&oa[0];
      *(float4*)&ob[(size_t)256 * C_ + base] = *(float4*)&o2[0];
      *(float4*)&ob[(size_t)384 * C_ + base] = *(float4*)&o3[0];
    }
  }
}

// ---------------------------------------------------------------------------
extern "C" void kernel_launch(void* const* d_in, const int* in_sizes, int n_in,
                              void* d_out, int out_size, void* d_ws, size_t ws_size,
                              hipStream_t stream) {
  const float* c     = (const float*)d_in[0];
  const float* q     = (const float*)d_in[1];
  const float* cmask = (const float*)d_in[2];
  const float* qmask = (const float*)d_in[3];
  const float* ctxw  = (const float*)d_in[4];
  const float* qw    = (const float*)d_in[5];
  const float* cqw   = (const float*)d_in[6];
  const float* bias  = (const float*)d_in[7];
  float* out = (float*)d_out;

  float* ws      = (float*)d_ws;
  float* S       = ws;                                   // B*C*Q = 8388608
  float* s1b     = S + (size_t)B_ * C_ * Q_;             // B*Q
  float* rowmax  = s1b + B_ * Q_;                        // B*C
  float* rowsum  = rowmax + B_ * C_;                     // B*C
  float* partmax = rowsum + B_ * C_;                     // B*16*Q
  float* partsum = partmax + B_ * 16 * Q_;               // B*16*Q
  float* colmax  = partsum + B_ * 16 * Q_;               // B*Q
  float* colsum  = colmax + B_ * Q_;                     // B*Q
  float* Tpart   = colsum + B_ * Q_;                     // 4*B*Q*H
  float* T       = Tpart + (size_t)4 * B_ * Q_ * H_;     // B*Q*H

  hipLaunchKernelGGL(k0_s1b, dim3(B_), dim3(128), 0, stream, q, qw, bias, s1b);
  hipLaunchKernelGGL(k1_S, dim3(C_ / 128, B_), dim3(256), 0, stream,
                     c, q, ctxw, cqw, s1b, S);
  hipLaunchKernelGGL(k2_stats, dim3(C_ / 64, B_), dim3(256), 0, stream,
                     S, cmask, qmask, rowmax, rowsum, partmax, partsum);
  hipLaunchKernelGGL(k2b_combine, dim3(B_), dim3(128), 0, stream,
                     partmax, partsum, colmax, colsum);
  hipLaunchKernelGGL(k3_T, dim3(4, B_), dim3(256), 0, stream,
                     S, c, cmask, colmax, Tpart);
  hipLaunchKernelGGL(k3b_combine, dim3((B_ * Q_ * H_) / 256), dim3(256), 0, stream,
                     Tpart, colsum, T);
  hipLaunchKernelGGL(k4_out, dim3(C_ / 128, 2, B_), dim3(256), 0, stream,
                     S, q, c, T, rowmax, rowsum, qmask, out);
}

// Round 2
// 344.876 us; speedup vs baseline: 1.0001x; 1.0001x over previous
//
#include <hip/hip_runtime.h>
#include <math.h>

#define NEG_HUGE -1e30f
constexpr int B_ = 64, H_ = 128, C_ = 1024, Q_ = 128;

typedef __bf16 bf16x8 __attribute__((ext_vector_type(8)));
typedef float f32x4 __attribute__((ext_vector_type(4)));
typedef short short8 __attribute__((ext_vector_type(8)));
typedef short short4s __attribute__((ext_vector_type(4)));

__device__ __forceinline__ float bs2f(short s) {
  unsigned u = ((unsigned)(unsigned short)s) << 16;
  float f; __builtin_memcpy(&f, &u, 4); return f;
}
__device__ __forceinline__ short f2bs(float f) {
  unsigned u; __builtin_memcpy(&u, &f, 4);
  u = (u + 0x7fffu + ((u >> 16) & 1u)) >> 16;
  return (short)u;
}

// ---------------------------------------------------------------------------
// kTc: cT[b][c][h] (bf16) = cin[b][h][c].  grid (16,2,B), block 256.
// ---------------------------------------------------------------------------
__global__ __launch_bounds__(256) void kTc(const float* __restrict__ cin,
                                           short* __restrict__ cT) {
  __shared__ float T[64 * 69];
  const int t = threadIdx.x;
  const int c0 = blockIdx.x * 64, h0 = blockIdx.y * 64, b = blockIdx.z;
  {
    const int row = t >> 2, off = t & 3;
    const float* src = cin + (b * H_ + h0 + row) * C_ + c0;
#pragma unroll
    for (int j = 0; j < 4; ++j) {
      float4 v = *(const float4*)&src[off * 16 + j * 4];
      int cbase = off * 16 + j * 4;
      T[row * 69 + cbase + 0] = v.x;
      T[row * 69 + cbase + 1] = v.y;
      T[row * 69 + cbase + 2] = v.z;
      T[row * 69 + cbase + 3] = v.w;
    }
  }
  __syncthreads();
  {
    const int c = t >> 2, offh = t & 3;
    short* dst = cT + (b * C_ + c0 + c) * H_ + h0;
#pragma unroll
    for (int j = 0; j < 4; ++j) {
      int hs = offh * 16 + j * 4;
      short4s v;
      v[0] = f2bs(T[(hs + 0) * 69 + c]);
      v[1] = f2bs(T[(hs + 1) * 69 + c]);
      v[2] = f2bs(T[(hs + 2) * 69 + c]);
      v[3] = f2bs(T[(hs + 3) * 69 + c]);
      *(short4s*)&dst[hs] = v;
    }
  }
}

// ---------------------------------------------------------------------------
// kq: qTw[b][q][h] (bf16) = qin[b][h][q]*cqw[h];  s1m[b][q] = q.qw + qmask.
// grid (2,B), block 256.
// ---------------------------------------------------------------------------
__global__ __launch_bounds__(256) void kq(const float* __restrict__ qin,
                                          const float* __restrict__ qw,
                                          const float* __restrict__ cqw,
                                          const float* __restrict__ qmask,
                                          short* __restrict__ qTw,
                                          float* __restrict__ s1m) {
  __shared__ float T[64 * 130];  // [q-local][h]
  const int t = threadIdx.x;
  const int q0 = blockIdx.x * 64, b = blockIdx.y;
#pragma unroll
  for (int p = 0; p < 8; ++p) {
    int fidx = t + 256 * p;
    int h = fidx >> 4, seg = fidx & 15;
    float4 v = *(const float4*)&qin[(b * H_ + h) * Q_ + q0 + seg * 4];
    T[(seg * 4 + 0) * 130 + h] = v.x;
    T[(seg * 4 + 1) * 130 + h] = v.y;
    T[(seg * 4 + 2) * 130 + h] = v.z;
    T[(seg * 4 + 3) * 130 + h] = v.w;
  }
  __syncthreads();
  if (t < 64) {
    float acc = 0.f;
#pragma unroll 8
    for (int h = 0; h < 128; ++h) acc += T[t * 130 + h] * qw[h];
    float qm = (qmask[b * Q_ + q0 + t] > 0.f) ? 0.f : NEG_HUGE;
    s1m[b * Q_ + q0 + t] = acc + qm;
  }
  {
    const int q = t >> 2, off = t & 3;
    short* dst = qTw + (b * Q_ + q0 + q) * H_;
#pragma unroll
    for (int j = 0; j < 4; ++j) {
      int hbv = off * 32 + j * 8;
      short8 v;
#pragma unroll
      for (int i = 0; i < 8; ++i) v[i] = f2bs(T[q * 130 + hbv + i] * cqw[hbv + i]);
      *(short8*)&dst[hbv] = v;
    }
  }
}

// ---------------------------------------------------------------------------
// k1: MFMA s2-tile (128c x 128q), fused row softmax -> a_att bf16,
// fused col partial stats + eP bf16 (transposed), fused s0.
// grid (8, B), block 256.
// ---------------------------------------------------------------------------
__global__ __launch_bounds__(256) void k1_mfma(
    const short* __restrict__ cT, const short* __restrict__ qTw,
    const float* __restrict__ s1m, const float* __restrict__ cmask,
    const float* __restrict__ ctxw,
    short* __restrict__ a_att, short* __restrict__ ePT,
    float* __restrict__ pcm, float* __restrict__ pcs) {
  __shared__ __align__(16) char uni[34816];
  __shared__ float s1mL[128], scolL[128], red[256], pw[512], mpL[128];
  short* AL = (short*)uni;            // [128][40] bf16
  short* BL = (short*)(uni + 10240);  // [128][40] bf16
  short* RP = (short*)uni;            // [128][136] bf16 (after K-loop)

  const int t = threadIdx.x;
  const int w = t >> 6, l = t & 63, quad = l >> 4, lcol = l & 15;
  const int bx = blockIdx.x, b = blockIdx.y, c0 = bx * 128;

  if (t < 128) {
    s1mL[t] = s1m[b * Q_ + t];
    scolL[t] = (cmask[b * C_ + c0 + t] > 0.f) ? 0.f : NEG_HUGE;
  }

  f32x4 acc[2][8];
#pragma unroll
  for (int mt = 0; mt < 2; ++mt)
#pragma unroll
    for (int nt = 0; nt < 8; ++nt) acc[mt][nt] = (f32x4){0.f, 0.f, 0.f, 0.f};

  float s0p = 0.f;
  const int ar = t >> 2, aoff = t & 3;
  const int sr = t & 127, sh = (t >> 7) * 16;

  for (int kc = 0; kc < 4; ++kc) {
    const int h0 = kc * 32;
    *(short8*)&AL[ar * 40 + aoff * 8] =
        *(const short8*)&cT[(b * C_ + c0 + ar) * H_ + h0 + aoff * 8];
    *(short8*)&AL[(64 + ar) * 40 + aoff * 8] =
        *(const short8*)&cT[(b * C_ + c0 + 64 + ar) * H_ + h0 + aoff * 8];
    *(short8*)&BL[ar * 40 + aoff * 8] =
        *(const short8*)&qTw[(b * Q_ + ar) * H_ + h0 + aoff * 8];
    *(short8*)&BL[(64 + ar) * 40 + aoff * 8] =
        *(const short8*)&qTw[(b * Q_ + 64 + ar) * H_ + h0 + aoff * 8];
    __syncthreads();
    // fused s0 partial (c-values pass through LDS anyway)
#pragma unroll
    for (int j = 0; j < 16; ++j)
      s0p += bs2f(AL[sr * 40 + sh + j]) * ctxw[h0 + sh + j];
    bf16x8 af0 = *(bf16x8*)&AL[(w * 32 + lcol) * 40 + quad * 8];
    bf16x8 af1 = *(bf16x8*)&AL[(w * 32 + 16 + lcol) * 40 + quad * 8];
#pragma unroll
    for (int nt = 0; nt < 8; ++nt) {
      bf16x8 bfrag = *(bf16x8*)&BL[(nt * 16 + lcol) * 40 + quad * 8];
      acc[0][nt] = __builtin_amdgcn_mfma_f32_16x16x32_bf16(af0, bfrag, acc[0][nt], 0, 0, 0);
      acc[1][nt] = __builtin_amdgcn_mfma_f32_16x16x32_bf16(af1, bfrag, acc[1][nt], 0, 0, 0);
    }
    __syncthreads();
  }

  red[t] = s0p;

  // ---- row softmax (in-register; s0/bias cancel over q) ----
  float s1v[8];
#pragma unroll
  for (int nt = 0; nt < 8; ++nt) s1v[nt] = s1mL[nt * 16 + lcol];
  float rm[2][4], inv[2][4];
#pragma unroll
  for (int mt = 0; mt < 2; ++mt)
#pragma unroll
    for (int r = 0; r < 4; ++r) {
      float m = -INFINITY;
#pragma unroll
      for (int nt = 0; nt < 8; ++nt) m = fmaxf(m, acc[mt][nt][r] + s1v[nt]);
      rm[mt][r] = m;
    }
#pragma unroll
  for (int d = 1; d <= 8; d <<= 1)
#pragma unroll
    for (int mt = 0; mt < 2; ++mt)
#pragma unroll
      for (int r = 0; r < 4; ++r)
        rm[mt][r] = fmaxf(rm[mt][r], __shfl_xor(rm[mt][r], d));
#pragma unroll
  for (int mt = 0; mt < 2; ++mt)
#pragma unroll
    for (int r = 0; r < 4; ++r) {
      float s = 0.f;
#pragma unroll
      for (int nt = 0; nt < 8; ++nt)
        s += __expf(acc[mt][nt][r] + s1v[nt] - rm[mt][r]);
      inv[mt][r] = s;
    }
#pragma unroll
  for (int d = 1; d <= 8; d <<= 1)
#pragma unroll
    for (int mt = 0; mt < 2; ++mt)
#pragma unroll
      for (int r = 0; r < 4; ++r)
        inv[mt][r] += __shfl_xor(inv[mt][r], d);
#pragma unroll
  for (int mt = 0; mt < 2; ++mt)
#pragma unroll
    for (int r = 0; r < 4; ++r) inv[mt][r] = 1.f / inv[mt][r];

  __syncthreads();  // (A) red done; frag reads of AL/BL done
  if (t < 128) scolL[t] += red[t] + red[t + 128];  // s0 + cmask term

  // repack normalized a_att -> RP[c][q]
#pragma unroll
  for (int mt = 0; mt < 2; ++mt)
#pragma unroll
    for (int nt = 0; nt < 8; ++nt)
#pragma unroll
      for (int r = 0; r < 4; ++r) {
        int row = w * 32 + mt * 16 + quad * 4 + r;
        int col = nt * 16 + lcol;
        float v = __expf(acc[mt][nt][r] + s1v[nt] - rm[mt][r]) * inv[mt][r];
        RP[row * 136 + col] = f2bs(v);
      }
  __syncthreads();  // (B)
  {
    const int row = t >> 1, half = t & 1;
    short* dst = a_att + (b * C_ + c0 + row) * Q_ + half * 64;
    const short* srcp = RP + row * 136 + half * 64;
#pragma unroll
    for (int j = 0; j < 8; ++j) *(short8*)&dst[j * 8] = *(const short8*)&srcp[j * 8];
  }

  // ---- column partial stats (s1/bias cancel over c) ----
  float cs0[2][4];
#pragma unroll
  for (int mt = 0; mt < 2; ++mt)
#pragma unroll
    for (int r = 0; r < 4; ++r)
      cs0[mt][r] = scolL[w * 32 + mt * 16 + quad * 4 + r];
  float pmv[8];
#pragma unroll
  for (int nt = 0; nt < 8; ++nt) {
    float m = -INFINITY;
#pragma unroll
    for (int mt = 0; mt < 2; ++mt)
#pragma unroll
      for (int r = 0; r < 4; ++r) m = fmaxf(m, acc[mt][nt][r] + cs0[mt][r]);
    pmv[nt] = m;
  }
#pragma unroll
  for (int nt = 0; nt < 8; ++nt) {
    pmv[nt] = fmaxf(pmv[nt], __shfl_xor(pmv[nt], 16));
    pmv[nt] = fmaxf(pmv[nt], __shfl_xor(pmv[nt], 32));
  }
  if (l < 16) {
#pragma unroll
    for (int nt = 0; nt < 8; ++nt) pw[w * 128 + nt * 16 + lcol] = pmv[nt];
  }
  __syncthreads();  // (C)
  if (t < 128) {
    float m = fmaxf(fmaxf(pw[t], pw[128 + t]), fmaxf(pw[256 + t], pw[384 + t]));
    mpL[t] = m;
    pcm[(b * 8 + bx) * Q_ + t] = m;
  }
  __syncthreads();  // (D)
  float mpv[8];
#pragma unroll
  for (int nt = 0; nt < 8; ++nt) mpv[nt] = mpL[nt * 16 + lcol];
  float psv[8];
#pragma unroll
  for (int nt = 0; nt < 8; ++nt) {
    float s = 0.f;
#pragma unroll
    for (int mt = 0; mt < 2; ++mt)
#pragma unroll
      for (int r = 0; r < 4; ++r)
        s += __expf(acc[mt][nt][r] + cs0[mt][r] - mpv[nt]);
    psv[nt] = s;
  }
#pragma unroll
  for (int nt = 0; nt < 8; ++nt) {
    psv[nt] += __shfl_xor(psv[nt], 16);
    psv[nt] += __shfl_xor(psv[nt], 32);
  }
  if (l < 16) {
#pragma unroll
    for (int nt = 0; nt < 8; ++nt) pw[w * 128 + nt * 16 + lcol] = psv[nt];
  }
  __syncthreads();  // (E)
  if (t < 128) pcs[(b * 8 + bx) * Q_ + t] = pw[t] + pw[128 + t] + pw[256 + t] + pw[384 + t];

  // repack eP transposed -> RP[q][c-local]
#pragma unroll
  for (int mt = 0; mt < 2; ++mt)
#pragma unroll
    for (int nt = 0; nt < 8; ++nt)
#pragma unroll
      for (int r = 0; r < 4; ++r) {
        int qq = nt * 16 + lcol;
        int cl = w * 32 + mt * 16 + quad * 4 + r;
        float v = __expf(acc[mt][nt][r] + cs0[mt][r] - mpv[nt]);
        RP[qq * 136 + cl] = f2bs(v);
      }
  __syncthreads();  // (F)
  {
    const int qq = t >> 1, half = t & 1;
    short* dst = ePT + (b * Q_ + qq) * C_ + c0 + half * 64;
    const short* srcp = RP + qq * 136 + half * 64;
#pragma unroll
    for (int j = 0; j < 8; ++j) *(short8*)&dst[j * 8] = *(const short8*)&srcp[j * 8];
  }
}

// ---------------------------------------------------------------------------
// k2b: combine 8 column partials -> per-tile scale + 1/colsum. grid B, 128.
// ---------------------------------------------------------------------------
__global__ __launch_bounds__(128) void k2b(const float* __restrict__ pcm,
                                           const float* __restrict__ pcs,
                                           float* __restrict__ scale_t,
                                           float* __restrict__ inv_cs) {
  const int b = blockIdx.x, q = threadIdx.x;
  float m[8]; float M = -INFINITY;
#pragma unroll
  for (int k = 0; k < 8; ++k) { m[k] = pcm[(b * 8 + k) * Q_ + q]; M = fmaxf(M, m[k]); }
  float s = 0.f;
#pragma unroll
  for (int k = 0; k < 8; ++k) {
    float sc = __expf(m[k] - M);
    scale_t[(b * 8 + k) * Q_ + q] = sc;
    s += pcs[(b * 8 + k) * Q_ + q] * sc;
  }
  inv_cs[b * Q_ + q] = 1.f / s;
}

// ---------------------------------------------------------------------------
// k3: TmT[b][h][q] (bf16) = (1/colsum) * sum_c eP*scale * c.  grid (2,B), 256.
// ---------------------------------------------------------------------------
__global__ __launch_bounds__(256) void k3_T(
    const short* __restrict__ ePT, const float* __restrict__ cin,
    const float* __restrict__ scale_t, const float* __restrict__ inv_cs,
    short* __restrict__ TmT) {
  __shared__ __align__(16) char uni[17408];
  __shared__ float scL[1024], icL[128];
  short* AL = (short*)uni;            // [128][40]
  short* BL = (short*)(uni + 10240);  // [64][40]
  short* RP = (short*)uni;            // [64][136]
  const int t = threadIdx.x;
  const int w = t >> 6, l = t & 63, quad = l >> 4, lcol = l & 15;
  const int hb = blockIdx.x * 64, b = blockIdx.y;
#pragma unroll
  for (int i = 0; i < 4; ++i) scL[t + 256 * i] = scale_t[b * 1024 + t + 256 * i];
  if (t < 128) icL[t] = inv_cs[b * Q_ + t];
  __syncthreads();

  f32x4 acc[2][4];
#pragma unroll
  for (int mt = 0; mt < 2; ++mt)
#pragma unroll
    for (int nt = 0; nt < 4; ++nt) acc[mt][nt] = (f32x4){0.f, 0.f, 0.f, 0.f};

  const int ar = t >> 2, aoff = t & 3;
  for (int ct = 0; ct < 8; ++ct) {
    const float sc0 = scL[ct * 128 + ar];
    const float sc1 = scL[ct * 128 + 64 + ar];
    for (int kc = 0; kc < 4; ++kc) {
      const int coff = ct * 128 + kc * 32;
      {
        short8 v = *(const short8*)&ePT[(b * Q_ + ar) * C_ + coff + aoff * 8];
        short8 o;
#pragma unroll
        for (int i = 0; i < 8; ++i) o[i] = f2bs(bs2f(v[i]) * sc0);
        *(short8*)&AL[ar * 40 + aoff * 8] = o;
        v = *(const short8*)&ePT[(b * Q_ + 64 + ar) * C_ + coff + aoff * 8];
#pragma unroll
        for (int i = 0; i < 8; ++i) o[i] = f2bs(bs2f(v[i]) * sc1);
        *(short8*)&AL[(64 + ar) * 40 + aoff * 8] = o;
      }
      {
        const float* srcp = cin + (b * H_ + hb + ar) * C_ + coff + aoff * 8;
        short8 o;
#pragma unroll
        for (int i = 0; i < 8; ++i) o[i] = f2bs(srcp[i]);
        *(short8*)&BL[ar * 40 + aoff * 8] = o;
      }
      __syncthreads();
      bf16x8 af0 = *(bf16x8*)&AL[(w * 32 + lcol) * 40 + quad * 8];
      bf16x8 af1 = *(bf16x8*)&AL[(w * 32 + 16 + lcol) * 40 + quad * 8];
#pragma unroll
      for (int nt = 0; nt < 4; ++nt) {
        bf16x8 bfrag = *(bf16x8*)&BL[(nt * 16 + lcol) * 40 + quad * 8];
        acc[0][nt] = __builtin_amdgcn_mfma_f32_16x16x32_bf16(af0, bfrag, acc[0][nt], 0, 0, 0);
        acc[1][nt] = __builtin_amdgcn_mfma_f32_16x16x32_bf16(af1, bfrag, acc[1][nt], 0, 0, 0);
      }
      __syncthreads();
    }
  }
#pragma unroll
  for (int mt = 0; mt < 2; ++mt)
#pragma unroll
    for (int nt = 0; nt < 4; ++nt)
#pragma unroll
      for (int r = 0; r < 4; ++r) {
        int qq = w * 32 + mt * 16 + quad * 4 + r;
        int hl = nt * 16 + lcol;
        RP[hl * 136 + qq] = f2bs(acc[mt][nt][r] * icL[qq]);
      }
  __syncthreads();
  {
    const int hl = t >> 2, seg = t & 3;
    short* dst = TmT + (b * H_ + hb + hl) * Q_ + seg * 32;
    const short* srcp = RP + hl * 136 + seg * 32;
#pragma unroll
    for (int j = 0; j < 4; ++j) *(short8*)&dst[j * 8] = *(const short8*)&srcp[j * 8];
  }
}

// ---------------------------------------------------------------------------
// k4: a = a_att@qT, b = a_att@Tm (MFMA); emit [c, a, c*a, c*b].
// grid (8, 2, B), block 256.
// ---------------------------------------------------------------------------
__global__ __launch_bounds__(256) void k4_out(
    const short* __restrict__ a_att, const float* __restrict__ qin,
    const short* __restrict__ TmT, const float* __restrict__ cin,
    float* __restrict__ out) {
  __shared__ __align__(16) char uni[34816];
  short* AL = (short*)uni;             // [128][40]
  short* B1 = (short*)(uni + 10240);   // [64][40]
  short* B2 = (short*)(uni + 15360);   // [64][40]
  float* RPF = (float*)uni;            // [64][136] f32
  const int t = threadIdx.x;
  const int w = t >> 6, l = t & 63, quad = l >> 4, lcol = l & 15;
  const int c0 = blockIdx.x * 128, hb = blockIdx.y * 64, b = blockIdx.z;

  f32x4 accA[2][4], accB[2][4];
#pragma unroll
  for (int mt = 0; mt < 2; ++mt)
#pragma unroll
    for (int nt = 0; nt < 4; ++nt) {
      accA[mt][nt] = (f32x4){0.f, 0.f, 0.f, 0.f};
      accB[mt][nt] = (f32x4){0.f, 0.f, 0.f, 0.f};
    }

  const int ar = t >> 2, aoff = t & 3;
  for (int kc = 0; kc < 4; ++kc) {
    const int q0 = kc * 32;
    *(short8*)&AL[ar * 40 + aoff * 8] =
        *(const short8*)&a_att[(b * C_ + c0 + ar) * Q_ + q0 + aoff * 8];
    *(short8*)&AL[(64 + ar) * 40 + aoff * 8] =
        *(const short8*)&a_att[(b * C_ + c0 + 64 + ar) * Q_ + q0 + aoff * 8];
    {
      const float* srcp = qin + (b * H_ + hb + ar) * Q_ + q0 + aoff * 8;
      short8 o;
#pragma unroll
      for (int i = 0; i < 8; ++i) o[i] = f2bs(srcp[i]);
      *(short8*)&B1[ar * 40 + aoff * 8] = o;
    }
    *(short8*)&B2[ar * 40 + aoff * 8] =
        *(const short8*)&TmT[(b * H_ + hb + ar) * Q_ + q0 + aoff * 8];
    __syncthreads();
    bf16x8 af0 = *(bf16x8*)&AL[(w * 32 + lcol) * 40 + quad * 8];
    bf16x8 af1 = *(bf16x8*)&AL[(w * 32 + 16 + lcol) * 40 + quad * 8];
#pragma unroll
    for (int nt = 0; nt < 4; ++nt) {
      bf16x8 bq = *(bf16x8*)&B1[(nt * 16 + lcol) * 40 + quad * 8];
      bf16x8 bt = *(bf16x8*)&B2[(nt * 16 + lcol) * 40 + quad * 8];
      accA[0][nt] = __builtin_amdgcn_mfma_f32_16x16x32_bf16(af0, bq, accA[0][nt], 0, 0, 0);
      accA[1][nt] = __builtin_amdgcn_mfma_f32_16x16x32_bf16(af1, bq, accA[1][nt], 0, 0, 0);
      accB[0][nt] = __builtin_amdgcn_mfma_f32_16x16x32_bf16(af0, bt, accB[0][nt], 0, 0, 0);
      accB[1][nt] = __builtin_amdgcn_mfma_f32_16x16x32_bf16(af1, bt, accB[1][nt], 0, 0, 0);
    }
    __syncthreads();
  }

  const int hl = t >> 2, off = t & 3;
  const int hrow = hb + hl;
  float* ob = out + (size_t)b * 512 * 1024;

  // pass A: slabs c, a, c*a
#pragma unroll
  for (int mt = 0; mt < 2; ++mt)
#pragma unroll
    for (int nt = 0; nt < 4; ++nt)
#pragma unroll
      for (int r = 0; r < 4; ++r)
        RPF[(nt * 16 + lcol) * 136 + (w * 32 + mt * 16 + quad * 4 + r)] = accA[mt][nt][r];
  __syncthreads();
#pragma unroll
  for (int j = 0; j < 8; ++j) {
    int col = off * 32 + j * 4;
    float4 la = *(float4*)&RPF[hl * 136 + col];
    float4 cv = *(const float4*)&cin[(b * H_ + hrow) * C_ + c0 + col];
    *(float4*)&ob[(size_t)hrow * 1024 + c0 + col] = cv;
    *(float4*)&ob[(size_t)(128 + hrow) * 1024 + c0 + col] = la;
    float4 p = make_float4(cv.x * la.x, cv.y * la.y, cv.z * la.z, cv.w * la.w);
    *(float4*)&ob[(size_t)(256 + hrow) * 1024 + c0 + col] = p;
  }
  __syncthreads();
  // pass B: slab c*b
#pragma unroll
  for (int mt = 0; mt < 2; ++mt)
#pragma unroll
    for (int nt = 0; nt < 4; ++nt)
#pragma unroll
      for (int r = 0; r < 4; ++r)
        RPF[(nt * 16 + lcol) * 136 + (w * 32 + mt * 16 + quad * 4 + r)] = accB[mt][nt][r];
  __syncthreads();
#pragma unroll
  for (int j = 0; j < 8; ++j) {
    int col = off * 32 + j * 4;
    float4 lb = *(float4*)&RPF[hl * 136 + col];
    float4 cv = *(const float4*)&cin[(b * H_ + hrow) * C_ + c0 + col];
    float4 p = make_float4(cv.x * lb.x, cv.y * lb.y, cv.z * lb.z, cv.w * lb.w);
    *(float4*)&ob[(size_t)(384 + hrow) * 1024 + c0 + col] = p;
  }
}

// ---------------------------------------------------------------------------
extern "C" void kernel_launch(void* const* d_in, const int* in_sizes, int n_in,
                              void* d_out, int out_size, void* d_ws, size_t ws_size,
                              hipStream_t stream) {
  const float* c     = (const float*)d_in[0];
  const float* q     = (const float*)d_in[1];
  const float* cmask = (const float*)d_in[2];
  const float* qmask = (const float*)d_in[3];
  const float* ctxw  = (const float*)d_in[4];
  const float* qw    = (const float*)d_in[5];
  const float* cqw   = (const float*)d_in[6];
  float* out = (float*)d_out;

  char* ws = (char*)d_ws;
  short* cT     = (short*)(ws);                       // 16,777,216 B
  short* qTw    = (short*)(ws + 16777216);            //  2,097,152 B
  short* a_att  = (short*)(ws + 18874368);            // 16,777,216 B
  short* ePT    = (short*)(ws + 35651584);            // 16,777,216 B
  short* TmT    = (short*)(ws + 52428800);            //  2,097,152 B
  float* s1m    = (float*)(ws + 54525952);            //     32,768 B
  float* pcm    = (float*)(ws + 54558720);            //    262,144 B
  float* pcs    = (float*)(ws + 54820864);            //    262,144 B
  float* scalet = (float*)(ws + 55083008);            //    262,144 B
  float* inv_cs = (float*)(ws + 55345152);            //     32,768 B

  kTc<<<dim3(16, 2, B_), dim3(256), 0, stream>>>(c, cT);
  kq<<<dim3(2, B_), dim3(256), 0, stream>>>(q, qw, cqw, qmask, qTw, s1m);
  k1_mfma<<<dim3(8, B_), dim3(256), 0, stream>>>(cT, qTw, s1m, cmask, ctxw,
                                                 a_att, ePT, pcm, pcs);
  k2b<<<dim3(B_), dim3(128), 0, stream>>>(pcm, pcs, scalet, inv_cs);
  k3_T<<<dim3(2, B_), dim3(256), 0, stream>>>(ePT, c, scalet, inv_cs, TmT);
  k4_out<<<dim3(8, 2, B_), dim3(256), 0, stream>>>(a_att, q, TmT, c, out);
}

// Round 3
// 263.224 us; speedup vs baseline: 1.3103x; 1.3102x over previous
//
#include <hip/hip_runtime.h>
#include <math.h>

#define NEG_HUGE -1e30f
constexpr int B_ = 64, H_ = 128, C_ = 1024, Q_ = 128;

typedef __bf16 bf16x8 __attribute__((ext_vector_type(8)));
typedef float f32x4 __attribute__((ext_vector_type(4)));
typedef short short8 __attribute__((ext_vector_type(8)));
typedef short short4s __attribute__((ext_vector_type(4)));

__device__ __forceinline__ float bs2f(short s) {
  unsigned u = ((unsigned)(unsigned short)s) << 16;
  float f; __builtin_memcpy(&f, &u, 4); return f;
}
__device__ __forceinline__ short f2bs(float f) {
  unsigned u; __builtin_memcpy(&u, &f, 4);
  u = (u + 0x7fffu + ((u >> 16) & 1u)) >> 16;
  return (short)u;
}

// ---------------------------------------------------------------------------
// kTc: cT[b][c][h] (bf16) = cin[b][h][c]; also s0 partials over its h-block.
// grid (16,2,B), block 256.
// ---------------------------------------------------------------------------
__global__ __launch_bounds__(256) void kTc(const float* __restrict__ cin,
                                           const float* __restrict__ ctxw,
                                           short* __restrict__ cT,
                                           float* __restrict__ s0p) {
  __shared__ float T[64 * 69];
  const int t = threadIdx.x;
  const int c0 = blockIdx.x * 64, h0 = blockIdx.y * 64, b = blockIdx.z;
  {
    const int row = t >> 2, off = t & 3;
    const float* src = cin + (b * H_ + h0 + row) * C_ + c0;
#pragma unroll
    for (int j = 0; j < 4; ++j) {
      float4 v = *(const float4*)&src[off * 16 + j * 4];
      int cbase = off * 16 + j * 4;
      T[row * 69 + cbase + 0] = v.x;
      T[row * 69 + cbase + 1] = v.y;
      T[row * 69 + cbase + 2] = v.z;
      T[row * 69 + cbase + 3] = v.w;
    }
  }
  __syncthreads();
  {
    const int c = t >> 2, offh = t & 3;
    short* dst = cT + (b * C_ + c0 + c) * H_ + h0;
#pragma unroll
    for (int j = 0; j < 4; ++j) {
      int hs = offh * 16 + j * 4;
      short4s v;
      v[0] = f2bs(T[(hs + 0) * 69 + c]);
      v[1] = f2bs(T[(hs + 1) * 69 + c]);
      v[2] = f2bs(T[(hs + 2) * 69 + c]);
      v[3] = f2bs(T[(hs + 3) * 69 + c]);
      *(short4s*)&dst[hs] = v;
    }
  }
  if (t < 64) {  // s0 partial for this h-block: sum_h c[h][c]*ctxw[h]
    float acc = 0.f;
#pragma unroll 8
    for (int h = 0; h < 64; ++h) acc += T[h * 69 + t] * ctxw[h0 + h];
    s0p[blockIdx.y * (B_ * C_) + b * C_ + c0 + t] = acc;
  }
}

// ---------------------------------------------------------------------------
// kq: qTw[b][q][h] = qin*cqw (bf16); qbf[b][h][q] = qin (bf16);
// s1m[b][q] = q.qw + qmask.  grid (2,B), block 256.
// ---------------------------------------------------------------------------
__global__ __launch_bounds__(256) void kq(const float* __restrict__ qin,
                                          const float* __restrict__ qw,
                                          const float* __restrict__ cqw,
                                          const float* __restrict__ qmask,
                                          short* __restrict__ qTw,
                                          short* __restrict__ qbf,
                                          float* __restrict__ s1m) {
  __shared__ float T[64 * 130];  // [q-local][h]
  const int t = threadIdx.x;
  const int q0 = blockIdx.x * 64, b = blockIdx.y;
#pragma unroll
  for (int p = 0; p < 8; ++p) {
    int fidx = t + 256 * p;
    int h = fidx >> 4, seg = fidx & 15;
    float4 v = *(const float4*)&qin[(b * H_ + h) * Q_ + q0 + seg * 4];
    T[(seg * 4 + 0) * 130 + h] = v.x;
    T[(seg * 4 + 1) * 130 + h] = v.y;
    T[(seg * 4 + 2) * 130 + h] = v.z;
    T[(seg * 4 + 3) * 130 + h] = v.w;
    short4s o; o[0] = f2bs(v.x); o[1] = f2bs(v.y); o[2] = f2bs(v.z); o[3] = f2bs(v.w);
    *(short4s*)&qbf[(b * H_ + h) * Q_ + q0 + seg * 4] = o;
  }
  __syncthreads();
  if (t < 64) {
    float acc = 0.f;
#pragma unroll 8
    for (int h = 0; h < 128; ++h) acc += T[t * 130 + h] * qw[h];
    float qm = (qmask[b * Q_ + q0 + t] > 0.f) ? 0.f : NEG_HUGE;
    s1m[b * Q_ + q0 + t] = acc + qm;
  }
  {
    const int q = t >> 2, off = t & 3;
    short* dst = qTw + (b * Q_ + q0 + q) * H_;
#pragma unroll
    for (int j = 0; j < 4; ++j) {
      int hbv = off * 32 + j * 8;
      short8 v;
#pragma unroll
      for (int i = 0; i < 8; ++i) v[i] = f2bs(T[q * 130 + hbv + i] * cqw[hbv + i]);
      *(short8*)&dst[hbv] = v;
    }
  }
}

// ---------------------------------------------------------------------------
// k1: MFMA s2-tile (128c x 128q), fused row softmax -> a_att bf16,
// fused col partial stats + eP bf16 (transposed).  grid (8, B), block 256.
// ---------------------------------------------------------------------------
__global__ __launch_bounds__(256) void k1_mfma(
    const short* __restrict__ cT, const short* __restrict__ qTw,
    const float* __restrict__ s1m, const float* __restrict__ cmask,
    const float* __restrict__ s0p,
    short* __restrict__ a_att, short* __restrict__ ePT,
    float* __restrict__ pcm, float* __restrict__ pcs) {
  __shared__ __align__(16) char uni[34816];
  __shared__ float s1mL[128], scolL[128], pw[512], mpL[128];
  short* AL = (short*)uni;            // [128][40] bf16
  short* BL = (short*)(uni + 10240);  // [128][40] bf16
  short* RP = (short*)uni;            // [128][136] bf16 (after K-loop)

  const int t = threadIdx.x;
  const int w = t >> 6, l = t & 63, quad = l >> 4, lcol = l & 15;
  const int bx = blockIdx.x, b = blockIdx.y, c0 = bx * 128;

  if (t < 128) {
    s1mL[t] = s1m[b * Q_ + t];
    float cm = (cmask[b * C_ + c0 + t] > 0.f) ? 0.f : NEG_HUGE;
    scolL[t] = cm + s0p[b * C_ + c0 + t] + s0p[B_ * C_ + b * C_ + c0 + t];
  }

  f32x4 acc[2][8];
#pragma unroll
  for (int mt = 0; mt < 2; ++mt)
#pragma unroll
    for (int nt = 0; nt < 8; ++nt) acc[mt][nt] = (f32x4){0.f, 0.f, 0.f, 0.f};

  const int ar = t >> 2, aoff = t & 3;

  for (int kc = 0; kc < 4; ++kc) {
    const int h0 = kc * 32;
    *(short8*)&AL[ar * 40 + aoff * 8] =
        *(const short8*)&cT[(b * C_ + c0 + ar) * H_ + h0 + aoff * 8];
    *(short8*)&AL[(64 + ar) * 40 + aoff * 8] =
        *(const short8*)&cT[(b * C_ + c0 + 64 + ar) * H_ + h0 + aoff * 8];
    *(short8*)&BL[ar * 40 + aoff * 8] =
        *(const short8*)&qTw[(b * Q_ + ar) * H_ + h0 + aoff * 8];
    *(short8*)&BL[(64 + ar) * 40 + aoff * 8] =
        *(const short8*)&qTw[(b * Q_ + 64 + ar) * H_ + h0 + aoff * 8];
    __syncthreads();
    bf16x8 af0 = *(bf16x8*)&AL[(w * 32 + lcol) * 40 + quad * 8];
    bf16x8 af1 = *(bf16x8*)&AL[(w * 32 + 16 + lcol) * 40 + quad * 8];
#pragma unroll
    for (int nt = 0; nt < 8; ++nt) {
      bf16x8 bfrag = *(bf16x8*)&BL[(nt * 16 + lcol) * 40 + quad * 8];
      acc[0][nt] = __builtin_amdgcn_mfma_f32_16x16x32_bf16(af0, bfrag, acc[0][nt], 0, 0, 0);
      acc[1][nt] = __builtin_amdgcn_mfma_f32_16x16x32_bf16(af1, bfrag, acc[1][nt], 0, 0, 0);
    }
    __syncthreads();
  }

  // ---- row softmax (in-register; s0/bias cancel over q) ----
  float s1v[8];
#pragma unroll
  for (int nt = 0; nt < 8; ++nt) s1v[nt] = s1mL[nt * 16 + lcol];
  float rm[2][4], inv[2][4];
#pragma unroll
  for (int mt = 0; mt < 2; ++mt)
#pragma unroll
    for (int r = 0; r < 4; ++r) {
      float m = -INFINITY;
#pragma unroll
      for (int nt = 0; nt < 8; ++nt) m = fmaxf(m, acc[mt][nt][r] + s1v[nt]);
      rm[mt][r] = m;
    }
#pragma unroll
  for (int d = 1; d <= 8; d <<= 1)
#pragma unroll
    for (int mt = 0; mt < 2; ++mt)
#pragma unroll
      for (int r = 0; r < 4; ++r)
        rm[mt][r] = fmaxf(rm[mt][r], __shfl_xor(rm[mt][r], d));
#pragma unroll
  for (int mt = 0; mt < 2; ++mt)
#pragma unroll
    for (int r = 0; r < 4; ++r) {
      float s = 0.f;
#pragma unroll
      for (int nt = 0; nt < 8; ++nt)
        s += __expf(acc[mt][nt][r] + s1v[nt] - rm[mt][r]);
      inv[mt][r] = s;
    }
#pragma unroll
  for (int d = 1; d <= 8; d <<= 1)
#pragma unroll
    for (int mt = 0; mt < 2; ++mt)
#pragma unroll
      for (int r = 0; r < 4; ++r)
        inv[mt][r] += __shfl_xor(inv[mt][r], d);
#pragma unroll
  for (int mt = 0; mt < 2; ++mt)
#pragma unroll
    for (int r = 0; r < 4; ++r) inv[mt][r] = 1.f / inv[mt][r];

  // repack normalized a_att -> RP[c][q]
#pragma unroll
  for (int mt = 0; mt < 2; ++mt)
#pragma unroll
    for (int nt = 0; nt < 8; ++nt)
#pragma unroll
      for (int r = 0; r < 4; ++r) {
        int row = w * 32 + mt * 16 + quad * 4 + r;
        int col = nt * 16 + lcol;
        float v = __expf(acc[mt][nt][r] + s1v[nt] - rm[mt][r]) * inv[mt][r];
        RP[row * 136 + col] = f2bs(v);
      }
  __syncthreads();  // (B)
  {
    const int row = t >> 1, half = t & 1;
    short* dst = a_att + (b * C_ + c0 + row) * Q_ + half * 64;
    const short* srcp = RP + row * 136 + half * 64;
#pragma unroll
    for (int j = 0; j < 8; ++j) *(short8*)&dst[j * 8] = *(const short8*)&srcp[j * 8];
  }

  // ---- column partial stats (s1/bias cancel over c) ----
  float cs0[2][4];
#pragma unroll
  for (int mt = 0; mt < 2; ++mt)
#pragma unroll
    for (int r = 0; r < 4; ++r)
      cs0[mt][r] = scolL[w * 32 + mt * 16 + quad * 4 + r];
  float pmv[8];
#pragma unroll
  for (int nt = 0; nt < 8; ++nt) {
    float m = -INFINITY;
#pragma unroll
    for (int mt = 0; mt < 2; ++mt)
#pragma unroll
      for (int r = 0; r < 4; ++r) m = fmaxf(m, acc[mt][nt][r] + cs0[mt][r]);
    pmv[nt] = m;
  }
#pragma unroll
  for (int nt = 0; nt < 8; ++nt) {
    pmv[nt] = fmaxf(pmv[nt], __shfl_xor(pmv[nt], 16));
    pmv[nt] = fmaxf(pmv[nt], __shfl_xor(pmv[nt], 32));
  }
  if (l < 16) {
#pragma unroll
    for (int nt = 0; nt < 8; ++nt) pw[w * 128 + nt * 16 + lcol] = pmv[nt];
  }
  __syncthreads();  // (C)
  if (t < 128) {
    float m = fmaxf(fmaxf(pw[t], pw[128 + t]), fmaxf(pw[256 + t], pw[384 + t]));
    mpL[t] = m;
    pcm[(b * 8 + bx) * Q_ + t] = m;
  }
  __syncthreads();  // (D)
  float mpv[8];
#pragma unroll
  for (int nt = 0; nt < 8; ++nt) mpv[nt] = mpL[nt * 16 + lcol];
  float psv[8];
#pragma unroll
  for (int nt = 0; nt < 8; ++nt) {
    float s = 0.f;
#pragma unroll
    for (int mt = 0; mt < 2; ++mt)
#pragma unroll
      for (int r = 0; r < 4; ++r)
        s += __expf(acc[mt][nt][r] + cs0[mt][r] - mpv[nt]);
    psv[nt] = s;
  }
#pragma unroll
  for (int nt = 0; nt < 8; ++nt) {
    psv[nt] += __shfl_xor(psv[nt], 16);
    psv[nt] += __shfl_xor(psv[nt], 32);
  }
  if (l < 16) {
#pragma unroll
    for (int nt = 0; nt < 8; ++nt) pw[w * 128 + nt * 16 + lcol] = psv[nt];
  }
  __syncthreads();  // (E)
  if (t < 128) pcs[(b * 8 + bx) * Q_ + t] = pw[t] + pw[128 + t] + pw[256 + t] + pw[384 + t];

  // repack eP transposed -> RP[q][c-local]
#pragma unroll
  for (int mt = 0; mt < 2; ++mt)
#pragma unroll
    for (int nt = 0; nt < 8; ++nt)
#pragma unroll
      for (int r = 0; r < 4; ++r) {
        int qq = nt * 16 + lcol;
        int cl = w * 32 + mt * 16 + quad * 4 + r;
        float v = __expf(acc[mt][nt][r] + cs0[mt][r] - mpv[nt]);
        RP[qq * 136 + cl] = f2bs(v);
      }
  __syncthreads();  // (F)
  {
    const int qq = t >> 1, half = t & 1;
    short* dst = ePT + (b * Q_ + qq) * C_ + c0 + half * 64;
    const short* srcp = RP + qq * 136 + half * 64;
#pragma unroll
    for (int j = 0; j < 8; ++j) *(short8*)&dst[j * 8] = *(const short8*)&srcp[j * 8];
  }
}

// ---------------------------------------------------------------------------
// k2b: combine 8 column partials -> per-tile scale + 1/colsum. grid B, 128.
// ---------------------------------------------------------------------------
__global__ __launch_bounds__(128) void k2b(const float* __restrict__ pcm,
                                           const float* __restrict__ pcs,
                                           float* __restrict__ scale_t,
                                           float* __restrict__ inv_cs) {
  const int b = blockIdx.x, q = threadIdx.x;
  float m[8]; float M = -INFINITY;
#pragma unroll
  for (int k = 0; k < 8; ++k) { m[k] = pcm[(b * 8 + k) * Q_ + q]; M = fmaxf(M, m[k]); }
  float s = 0.f;
#pragma unroll
  for (int k = 0; k < 8; ++k) {
    float sc = __expf(m[k] - M);
    scale_t[(b * 8 + k) * Q_ + q] = sc;
    s += pcs[(b * 8 + k) * Q_ + q] * sc;
  }
  inv_cs[b * Q_ + q] = 1.f / s;
}

// ---------------------------------------------------------------------------
// krs: ePT *= scale_t (in place, bf16). grid 4096, block 256, 8 elems/thread.
// ---------------------------------------------------------------------------
__global__ __launch_bounds__(256) void krs(short* __restrict__ ePT,
                                           const float* __restrict__ scale_t) {
  const int gid = blockIdx.x * 256 + threadIdx.x;
  const int e = gid * 8;
  const int c = e & 1023, q = (e >> 10) & 127, b = e >> 17;
  const float s = scale_t[(b * 8 + (c >> 7)) * Q_ + q];
  short8 v = *(short8*)&ePT[e];
  short8 o;
#pragma unroll
  for (int i = 0; i < 8; ++i) o[i] = f2bs(bs2f(v[i]) * s);
  *(short8*)&ePT[e] = o;
}

// ---------------------------------------------------------------------------
// k3: Tpart[kc][b][h][q] (f32) = sum_{c in kc-chunk} ePs[q][c] * c[h][c].
// grid (2 hb, 4 kc, B), block 256.
// ---------------------------------------------------------------------------
__global__ __launch_bounds__(256) void k3_T(
    const short* __restrict__ ePs, const float* __restrict__ cin,
    float* __restrict__ Tpart) {
  __shared__ __align__(16) char uni[34816];
  short* AL = (short*)uni;            // [128][40]
  short* BL = (short*)(uni + 10240);  // [64][40]
  float* RPF = (float*)uni;           // [64][136] f32 (after K-loop)
  const int t = threadIdx.x;
  const int w = t >> 6, l = t & 63, quad = l >> 4, lcol = l & 15;
  const int hb = blockIdx.x * 64, kc = blockIdx.y, b = blockIdx.z;

  f32x4 acc[2][4];
#pragma unroll
  for (int mt = 0; mt < 2; ++mt)
#pragma unroll
    for (int nt = 0; nt < 4; ++nt) acc[mt][nt] = (f32x4){0.f, 0.f, 0.f, 0.f};

  const int ar = t >> 2, aoff = t & 3;
  for (int ck = 0; ck < 8; ++ck) {
    const int coff = kc * 256 + ck * 32;
    *(short8*)&AL[ar * 40 + aoff * 8] =
        *(const short8*)&ePs[(b * Q_ + ar) * C_ + coff + aoff * 8];
    *(short8*)&AL[(64 + ar) * 40 + aoff * 8] =
        *(const short8*)&ePs[(b * Q_ + 64 + ar) * C_ + coff + aoff * 8];
    {
      const float* srcp = cin + (b * H_ + hb + ar) * C_ + coff + aoff * 8;
      short8 o;
#pragma unroll
      for (int i = 0; i < 8; ++i) o[i] = f2bs(srcp[i]);
      *(short8*)&BL[ar * 40 + aoff * 8] = o;
    }
    __syncthreads();
    bf16x8 af0 = *(bf16x8*)&AL[(w * 32 + lcol) * 40 + quad * 8];
    bf16x8 af1 = *(bf16x8*)&AL[(w * 32 + 16 + lcol) * 40 + quad * 8];
#pragma unroll
    for (int nt = 0; nt < 4; ++nt) {
      bf16x8 bfrag = *(bf16x8*)&BL[(nt * 16 + lcol) * 40 + quad * 8];
      acc[0][nt] = __builtin_amdgcn_mfma_f32_16x16x32_bf16(af0, bfrag, acc[0][nt], 0, 0, 0);
      acc[1][nt] = __builtin_amdgcn_mfma_f32_16x16x32_bf16(af1, bfrag, acc[1][nt], 0, 0, 0);
    }
    __syncthreads();
  }
  // RPF[h-local][q] then coalesced f32 stores
#pragma unroll
  for (int mt = 0; mt < 2; ++mt)
#pragma unroll
    for (int nt = 0; nt < 4; ++nt)
#pragma unroll
      for (int r = 0; r < 4; ++r)
        RPF[(nt * 16 + lcol) * 136 + (w * 32 + mt * 16 + quad * 4 + r)] = acc[mt][nt][r];
  __syncthreads();
  {
    float* Tp = Tpart + (size_t)kc * (B_ * H_ * Q_) + ((size_t)b * H_ + hb) * Q_;
    const int lr = t >> 5, coln = (t & 31) * 4;
#pragma unroll
    for (int iter = 0; iter < 8; ++iter) {
      int hl = iter * 8 + lr;
      *(float4*)&Tp[hl * Q_ + coln] = *(float4*)&RPF[hl * 136 + coln];
    }
  }
}

// ---------------------------------------------------------------------------
// k3b: TmT[b][h][q] (bf16) = (sum of 4 partials) * inv_cs[q]. grid 1024, 256.
// ---------------------------------------------------------------------------
__global__ __launch_bounds__(256) void k3b(const float* __restrict__ Tpart,
                                           const float* __restrict__ inv_cs,
                                           short* __restrict__ TmT) {
  const int gid = blockIdx.x * 256 + threadIdx.x;
  const int e = gid * 4;
  const int q0 = e & 127, b = e >> 14;
  float4 s = make_float4(0.f, 0.f, 0.f, 0.f);
#pragma unroll
  for (int k = 0; k < 4; ++k) {
    float4 v = *(const float4*)&Tpart[(size_t)k * (B_ * H_ * Q_) + e];
    s.x += v.x; s.y += v.y; s.z += v.z; s.w += v.w;
  }
  float4 ic = *(const float4*)&inv_cs[b * Q_ + q0];
  short4s o;
  o[0] = f2bs(s.x * ic.x); o[1] = f2bs(s.y * ic.y);
  o[2] = f2bs(s.z * ic.z); o[3] = f2bs(s.w * ic.w);
  *(short4s*)&TmT[e] = o;
}

// ---------------------------------------------------------------------------
// k4: a = a_att@qT, b = a_att@Tm (MFMA); emit [c, a, c*a, c*b].
// grid (8, 2, B), block 256. Coalesced row-major stores.
// ---------------------------------------------------------------------------
__global__ __launch_bounds__(256) void k4_out(
    const short* __restrict__ a_att, const short* __restrict__ qbf,
    const short* __restrict__ TmT, const float* __restrict__ cin,
    float* __restrict__ out) {
  __shared__ __align__(16) char uni[34816];
  short* AL = (short*)uni;             // [128][40]
  short* B1 = (short*)(uni + 10240);   // [64][40]
  short* B2 = (short*)(uni + 15360);   // [64][40]
  float* RPF = (float*)uni;            // [64][136] f32
  const int t = threadIdx.x;
  const int w = t >> 6, l = t & 63, quad = l >> 4, lcol = l & 15;
  const int c0 = blockIdx.x * 128, hb = blockIdx.y * 64, b = blockIdx.z;

  f32x4 accA[2][4], accB[2][4];
#pragma unroll
  for (int mt = 0; mt < 2; ++mt)
#pragma unroll
    for (int nt = 0; nt < 4; ++nt) {
      accA[mt][nt] = (f32x4){0.f, 0.f, 0.f, 0.f};
      accB[mt][nt] = (f32x4){0.f, 0.f, 0.f, 0.f};
    }

  const int ar = t >> 2, aoff = t & 3;
  for (int kc = 0; kc < 4; ++kc) {
    const int q0 = kc * 32;
    *(short8*)&AL[ar * 40 + aoff * 8] =
        *(const short8*)&a_att[(b * C_ + c0 + ar) * Q_ + q0 + aoff * 8];
    *(short8*)&AL[(64 + ar) * 40 + aoff * 8] =
        *(const short8*)&a_att[(b * C_ + c0 + 64 + ar) * Q_ + q0 + aoff * 8];
    *(short8*)&B1[ar * 40 + aoff * 8] =
        *(const short8*)&qbf[(b * H_ + hb + ar) * Q_ + q0 + aoff * 8];
    *(short8*)&B2[ar * 40 + aoff * 8] =
        *(const short8*)&TmT[(b * H_ + hb + ar) * Q_ + q0 + aoff * 8];
    __syncthreads();
    bf16x8 af0 = *(bf16x8*)&AL[(w * 32 + lcol) * 40 + quad * 8];
    bf16x8 af1 = *(bf16x8*)&AL[(w * 32 + 16 + lcol) * 40 + quad * 8];
#pragma unroll
    for (int nt = 0; nt < 4; ++nt) {
      bf16x8 bq = *(bf16x8*)&B1[(nt * 16 + lcol) * 40 + quad * 8];
      bf16x8 bt = *(bf16x8*)&B2[(nt * 16 + lcol) * 40 + quad * 8];
      accA[0][nt] = __builtin_amdgcn_mfma_f32_16x16x32_bf16(af0, bq, accA[0][nt], 0, 0, 0);
      accA[1][nt] = __builtin_amdgcn_mfma_f32_16x16x32_bf16(af1, bq, accA[1][nt], 0, 0, 0);
      accB[0][nt] = __builtin_amdgcn_mfma_f32_16x16x32_bf16(af0, bt, accB[0][nt], 0, 0, 0);
      accB[1][nt] = __builtin_amdgcn_mfma_f32_16x16x32_bf16(af1, bt, accB[1][nt], 0, 0, 0);
    }
    __syncthreads();
  }

  const int lr = t >> 5, coln = (t & 31) * 4;
  float* ob = out + (size_t)b * 512 * 1024;
  float4 cvv[8];

  // pass A: slabs c, a, c*a  (coalesced: 32 lanes cover one 512B row)
#pragma unroll
  for (int mt = 0; mt < 2; ++mt)
#pragma unroll
    for (int nt = 0; nt < 4; ++nt)
#pragma unroll
      for (int r = 0; r < 4; ++r)
        RPF[(nt * 16 + lcol) * 136 + (w * 32 + mt * 16 + quad * 4 + r)] = accA[mt][nt][r];
  __syncthreads();
#pragma unroll
  for (int iter = 0; iter < 8; ++iter) {
    int hl = iter * 8 + lr;
    int hrow = hb + hl;
    float4 la = *(float4*)&RPF[hl * 136 + coln];
    float4 cv = *(const float4*)&cin[(b * H_ + hrow) * C_ + c0 + coln];
    cvv[iter] = cv;
    *(float4*)&ob[(size_t)hrow * 1024 + c0 + coln] = cv;
    *(float4*)&ob[(size_t)(128 + hrow) * 1024 + c0 + coln] = la;
    float4 p = make_float4(cv.x * la.x, cv.y * la.y, cv.z * la.z, cv.w * la.w);
    *(float4*)&ob[(size_t)(256 + hrow) * 1024 + c0 + coln] = p;
  }
  __syncthreads();
  // pass B: slab c*b
#pragma unroll
  for (int mt = 0; mt < 2; ++mt)
#pragma unroll
    for (int nt = 0; nt < 4; ++nt)
#pragma unroll
      for (int r = 0; r < 4; ++r)
        RPF[(nt * 16 + lcol) * 136 + (w * 32 + mt * 16 + quad * 4 + r)] = accB[mt][nt][r];
  __syncthreads();
#pragma unroll
  for (int iter = 0; iter < 8; ++iter) {
    int hl = iter * 8 + lr;
    int hrow = hb + hl;
    float4 lb = *(float4*)&RPF[hl * 136 + coln];
    float4 cv = cvv[iter];
    float4 p = make_float4(cv.x * lb.x, cv.y * lb.y, cv.z * lb.z, cv.w * lb.w);
    *(float4*)&ob[(size_t)(384 + hrow) * 1024 + c0 + coln] = p;
  }
}

// ---------------------------------------------------------------------------
extern "C" void kernel_launch(void* const* d_in, const int* in_sizes, int n_in,
                              void* d_out, int out_size, void* d_ws, size_t ws_size,
                              hipStream_t stream) {
  const float* c     = (const float*)d_in[0];
  const float* q     = (const float*)d_in[1];
  const float* cmask = (const float*)d_in[2];
  const float* qmask = (const float*)d_in[3];
  const float* ctxw  = (const float*)d_in[4];
  const float* qw    = (const float*)d_in[5];
  const float* cqw   = (const float*)d_in[6];
  float* out = (float*)d_out;

  char* ws = (char*)d_ws;
  short* cT     = (short*)(ws);                       // 16,777,216 B (k1 input)
  float* Tpart  = (float*)(ws);                       // alias: cT dead after k1
  short* qTw    = (short*)(ws + 16777216);            //  2,097,152 B (k1 input)
  short* TmT    = (short*)(ws + 16777216);            // alias: qTw dead after k1
  short* qbf    = (short*)(ws + 18874368);            //  2,097,152 B
  short* a_att  = (short*)(ws + 20971520);            // 16,777,216 B
  short* ePT    = (short*)(ws + 37748736);            // 16,777,216 B
  float* s0p    = (float*)(ws + 54525952);            //    524,288 B
  float* s1m    = (float*)(ws + 55050240);            //     32,768 B
  float* pcm    = (float*)(ws + 55083008);            //    262,144 B
  float* pcs    = (float*)(ws + 55345152);            //    262,144 B
  float* scalet = (float*)(ws + 55607296);            //    262,144 B
  float* inv_cs = (float*)(ws + 55869440);            //     32,768 B

  kTc<<<dim3(16, 2, B_), dim3(256), 0, stream>>>(c, ctxw, cT, s0p);
  kq<<<dim3(2, B_), dim3(256), 0, stream>>>(q, qw, cqw, qmask, qTw, qbf, s1m);
  k1_mfma<<<dim3(8, B_), dim3(256), 0, stream>>>(cT, qTw, s1m, cmask, s0p,
                                                 a_att, ePT, pcm, pcs);
  k2b<<<dim3(B_), dim3(128), 0, stream>>>(pcm, pcs, scalet, inv_cs);
  krs<<<dim3(4096), dim3(256), 0, stream>>>(ePT, scalet);
  k3_T<<<dim3(2, 4, B_), dim3(256), 0, stream>>>(ePT, c, Tpart);
  k3b<<<dim3(1024), dim3(256), 0, stream>>>(Tpart, inv_cs, TmT);
  k4_out<<<dim3(8, 2, B_), dim3(256), 0, stream>>>(a_att, qbf, TmT, c, out);
}